// Round 6
// baseline (444.306 us; speedup 1.0000x reference)
//
#include <hip/hip_runtime.h>
#include <cstdint>
#include <cstddef>

typedef __bf16 bf16x8 __attribute__((ext_vector_type(8)));
typedef float f32x4 __attribute__((ext_vector_type(4)));
typedef unsigned short u16;
typedef unsigned short u16x8 __attribute__((ext_vector_type(8)));

#define BATCH 4096
#define NE 8

__device__ __forceinline__ u16 f2bf(float f) {
  union { float f; uint32_t u; } v; v.f = f;
  uint32_t u = v.u;
  u += 0x7fffu + ((u >> 16) & 1u);   // RTNE
  return (u16)(u >> 16);
}

__device__ __forceinline__ float bf2f(u16 u) {
  union { uint32_t u; float f; } v; v.u = ((uint32_t)u) << 16;
  return v.f;
}

__device__ __forceinline__ void cast8(const float* src, u16* dst) {
  const float4* p = (const float4*)src;
  float4 a = p[0], b = p[1];
  u16x8 o;
  o[0] = f2bf(a.x); o[1] = f2bf(a.y); o[2] = f2bf(a.z); o[3] = f2bf(a.w);
  o[4] = f2bf(b.x); o[5] = f2bf(b.y); o[6] = f2bf(b.z); o[7] = f2bf(b.w);
  *(u16x8*)dst = o;
}

// One dispatch: h0 = bf16(x); W0/W1/W2 (E,N,K0) fp32 -> Bt (N, E*K0) bf16.
__device__ __forceinline__ void conv_w_chunk(const float* __restrict__ W,
                                             u16* __restrict__ Bt,
                                             int N, int K0, int chunk) {
  int per_row = K0 >> 3;
  int rid = chunk / per_row;             // rid = e*N + o
  int i0 = (chunk - rid * per_row) << 3;
  int e = rid / N;
  int o = rid - e * N;
  cast8(W + (size_t)rid * K0 + i0,
        Bt + (size_t)o * ((size_t)NE * K0) + (size_t)e * K0 + i0);
}

__global__ void prep_kernel(const float* __restrict__ x,
                            const float* __restrict__ W0,
                            const float* __restrict__ W1,
                            const float* __restrict__ W2,
                            u16* __restrict__ h0, u16* __restrict__ Bt0,
                            u16* __restrict__ Bt1, u16* __restrict__ Bt2) {
  int t = blockIdx.x * blockDim.x + threadIdx.x;
  const int C0 = BATCH * 512 / 8;            // x cast:   262144
  const int C1 = C0 + NE * 1024 * 512 / 8;   // W0:      +524288
  const int C2 = C1 + NE * 1024 * 1024 / 8;  // W1:      +1048576
  if (t < C0) {
    cast8(x + (size_t)t * 8, h0 + (size_t)t * 8);
  } else if (t < C1) {
    conv_w_chunk(W0, Bt0, 1024, 512, t - C0);
  } else if (t < C2) {
    conv_w_chunk(W1, Bt1, 1024, 1024, t - C1);
  } else {
    conv_w_chunk(W2, Bt2, 512, 1024, t - C2);
  }
}

// out[b,o] = sum_e blend[b,e]*(P_e[b,o] + Bias[e,o]); optional ELU; bf16 or fp32 out.
template<bool ELU_ACT, bool OUT_BF16>
__global__ void combine8_kernel(const u16* __restrict__ P,
                                const float* __restrict__ blend,
                                const float* __restrict__ Bias,
                                void* __restrict__ outp, int N) {
  int t = blockIdx.x * blockDim.x + threadIdx.x;
  int per_row = N >> 3;
  int b = t / per_row;
  int i0 = (t - b * per_row) << 3;
  const size_t slice = (size_t)BATCH * N;
  const float4* blp = (const float4*)(blend + b * NE);
  float4 u0 = blp[0], u1 = blp[1];
  float bl[8] = {u0.x, u0.y, u0.z, u0.w, u1.x, u1.y, u1.z, u1.w};
  float v[8] = {0, 0, 0, 0, 0, 0, 0, 0};
  #pragma unroll
  for (int e = 0; e < NE; ++e) {
    u16x8 pv = *(const u16x8*)(P + (size_t)e * slice + (size_t)b * N + i0);
    #pragma unroll
    for (int j = 0; j < 8; ++j) v[j] += bl[e] * bf2f(pv[j]);
  }
  #pragma unroll
  for (int e = 0; e < NE; ++e) {
    const float4* bp = (const float4*)(Bias + (size_t)e * N + i0);
    float4 ba = bp[0], bb = bp[1];
    float bv[8] = {ba.x, ba.y, ba.z, ba.w, bb.x, bb.y, bb.z, bb.w};
    #pragma unroll
    for (int j = 0; j < 8; ++j) v[j] += bl[e] * bv[j];
  }
  if (ELU_ACT) {
    #pragma unroll
    for (int j = 0; j < 8; ++j) v[j] = v[j] > 0.f ? v[j] : expm1f(v[j]);
  }
  if (OUT_BF16) {
    u16x8 o;
    #pragma unroll
    for (int j = 0; j < 8; ++j) o[j] = f2bf(v[j]);
    *(u16x8*)((u16*)outp + (size_t)b * N + i0) = o;
  } else {
    float4* op = (float4*)((float*)outp + (size_t)b * N + i0);
    op[0] = (float4){v[0], v[1], v[2], v[3]};
    op[1] = (float4){v[4], v[5], v[6], v[7]};
  }
}

#define GL2LDS(g, l) __builtin_amdgcn_global_load_lds( \
    (__attribute__((address_space(1))) void*)(g),      \
    (__attribute__((address_space(3))) void*)(l), 16, 0, 0)

// Batched-expert GEMM: P_e(M x N) = h(M x K0) @ W_e(N x K0)^T, bf16 partials.
// blockIdx.z = expert. BM=BN=128, BK=64, 4 waves (2x2).
// A (h) staged via global_load_lds into XOR-8-swizzled LDS (0 conflicts, r5).
// B (Bt) fed DIRECTLY from global into VGPRs (AITER flatmm pattern): the
// 16x16x32 B-fragment is 16 contiguous bytes per lane of one Bt row, so a
// global_load_dwordx4 is the fragment load. This halves LDS port traffic,
// which round-5 counters showed to be the binding pipe (MfmaUtil 33% ==
// 155 cyc MFMA / ~500 cyc LDS per block-step).
// Epilogue: per-wave LDS transpose -> u16x8 coalesced stores (128B/8 lanes).
template<int K0>
__global__ __launch_bounds__(256, 3)
void gemm_be_kernel(const u16* __restrict__ h, const u16* __restrict__ Bt,
                    u16* __restrict__ P, int N) {
  __shared__ __align__(16) u16 Hs[128 * 64];   // 16 KB

  const int tid  = threadIdx.x;
  const int w    = tid >> 6, lane = tid & 63;
  const int wm   = w >> 1,   wn   = w & 1;
  const int lrow = lane & 15, quad = lane >> 4;

  const int row0 = blockIdx.x * 128;
  const int col0 = blockIdx.y * 128;
  const int e    = blockIdx.z;
  const int EK   = K0 * NE;

  // A staging: thread t covers 16B chunk (row = t>>3 + 32i, swizzled col)
  const int trow = tid >> 3;
  const int tcol = (tid & 7) ^ (trow & 7);
  const u16* gH = h + (size_t)(row0 + trow) * K0 + (tcol << 3);
  u16* lH = &Hs[tid * 8];

  // A fragment read pointers (XOR-8 swizzle), 2 kc x 4 mt
  const int xr = lrow & 7;
  const u16* fH[2][4];
  #pragma unroll
  for (int kc = 0; kc < 2; ++kc)
    #pragma unroll
    for (int i = 0; i < 4; ++i)
      fH[kc][i] = &Hs[(wm * 64 + i * 16 + lrow) * 64 + (((kc * 4 + quad) ^ xr) << 3)];

  // B fragment global pointers: 2 kc x 4 nt, 16B contiguous per lane
  const u16* gBf[8];
  #pragma unroll
  for (int kc = 0; kc < 2; ++kc)
    #pragma unroll
    for (int nt = 0; nt < 4; ++nt)
      gBf[kc * 4 + nt] = Bt + (size_t)(col0 + wn * 64 + nt * 16 + lrow) * EK
                            + (size_t)e * K0 + kc * 32 + quad * 8;

  f32x4 acc[4][4];
  #pragma unroll
  for (int i = 0; i < 4; ++i)
    #pragma unroll
    for (int j = 0; j < 4; ++j) acc[i][j] = (f32x4){0.f, 0.f, 0.f, 0.f};

  for (int it = 0; it < K0 / 64; ++it) {
    #pragma unroll
    for (int i = 0; i < 4; ++i)
      GL2LDS(gH + (size_t)(32 * i) * K0, lH + 2048 * i);
    gH += 64;
    // B fragments straight from global; the vmcnt(0) drain at the barrier
    // below completes them together with the A DMA.
    bf16x8 bfr[8];
    #pragma unroll
    for (int j = 0; j < 8; ++j)
      bfr[j] = *(const bf16x8*)(gBf[j] + it * 64);
    __syncthreads();

    #pragma unroll
    for (int kc = 0; kc < 2; ++kc) {
      bf16x8 hf[4];
      #pragma unroll
      for (int i = 0; i < 4; ++i) hf[i] = *(const bf16x8*)fH[kc][i];
      #pragma unroll
      for (int i = 0; i < 4; ++i)
        #pragma unroll
        for (int nt = 0; nt < 4; ++nt)
          acc[i][nt] = __builtin_amdgcn_mfma_f32_16x16x32_bf16(hf[i], bfr[kc * 4 + nt], acc[i][nt], 0, 0, 0);
    }
    __syncthreads();
  }

  // Coalesced epilogue via per-wave LDS transpose (Hs free after K-loop; the
  // final __syncthreads above guarantees all Hs reads are done).
  // C/D layout: col = lane&15, row = quad*4 + reg (m89/m91 verified).
  u16* Ps = P + (size_t)e * ((size_t)BATCH * N);
  u16* ls = &Hs[w * 2048];   // 4 KB per wave: 32 rows x 64 cols u16
  #pragma unroll
  for (int half = 0; half < 2; ++half) {
    #pragma unroll
    for (int mh = 0; mh < 2; ++mh) {
      int mt = half * 2 + mh;
      #pragma unroll
      for (int r = 0; r < 4; ++r) {
        int rloc = mh * 16 + quad * 4 + r;          // 0..31
        #pragma unroll
        for (int nt = 0; nt < 4; ++nt) {
          int col = nt * 16 + lrow;                 // 0..63
          int c8 = (col >> 3) ^ (rloc & 7);         // XOR-8 chunk swizzle
          ls[rloc * 64 + (c8 << 3) + (col & 7)] = f2bf(acc[mt][nt][r]);
        }
      }
    }
    // read back transposed: 4 passes of 64 lanes x 8 contiguous u16
    #pragma unroll
    for (int p = 0; p < 4; ++p) {
      int rloc = p * 8 + (lane >> 3);               // 0..31
      int c8 = (lane & 7) ^ (rloc & 7);
      u16x8 v = *(const u16x8*)&ls[rloc * 64 + (c8 << 3)];
      int row = row0 + wm * 64 + half * 32 + rloc;
      int colg = col0 + wn * 64 + ((lane & 7) << 3);
      *(u16x8*)&Ps[(size_t)row * N + colg] = v;
    }
  }
}

extern "C" void kernel_launch(void* const* d_in, const int* in_sizes, int n_in,
                              void* d_out, int out_size, void* d_ws, size_t ws_size,
                              hipStream_t stream) {
  const float* blend = (const float*)d_in[0];
  const float* x  = (const float*)d_in[1];
  const float* W0 = (const float*)d_in[2];
  const float* B0 = (const float*)d_in[3];
  const float* W1 = (const float*)d_in[4];
  const float* B1 = (const float*)d_in[5];
  const float* W2 = (const float*)d_in[6];
  const float* B2 = (const float*)d_in[7];
  float* out = (float*)d_out;

  char* ws = (char*)d_ws;
  u16* hA  = (u16*)ws;                           // h0 (4096x512) then h2 (4096x1024); 8.4 MB
  u16* h1  = (u16*)(ws + 8388608);               // 4096x1024 bf16, 8.4 MB
  u16* Bt0 = (u16*)(ws + 16777216);              // 1024 x 4096 bf16, 8.4 MB
  u16* Bt1 = (u16*)(ws + 25165824);              // 1024 x 8192 bf16, 16.8 MB
  u16* Bt2 = (u16*)(ws + 41943040);              // 512 x 8192 bf16, 8.4 MB
  u16* P   = (u16*)(ws + 50331648);              // bf16 partials, 8 x 4096 x 1024 = 67.1 MB

  // prep: cast x -> h0 and convert all three W to bf16 Bt layout (one dispatch)
  prep_kernel<<<9216, 256, 0, stream>>>(x, W0, W1, W2, hA, Bt0, Bt1, Bt2);

  // Layer 0: K0=512, N=1024; 8 expert slices; blend+bias+ELU in combine
  gemm_be_kernel<512><<<dim3(32, 8, 8), 256, 0, stream>>>(hA, Bt0, P, 1024);
  combine8_kernel<true, true><<<2048, 256, 0, stream>>>(P, blend, B0, h1, 1024);

  // Layer 1: K0=1024, N=1024
  gemm_be_kernel<1024><<<dim3(32, 8, 8), 256, 0, stream>>>(h1, Bt1, P, 1024);
  combine8_kernel<true, true><<<2048, 256, 0, stream>>>(P, blend, B1, hA, 1024);

  // Layer 2: K0=1024, N=512, linear, fp32 out
  gemm_be_kernel<1024><<<dim3(32, 4, 8), 256, 0, stream>>>(hA, Bt2, P, 512);
  combine8_kernel<false, false><<<1024, 256, 0, stream>>>(P, blend, B2, out, 512);
}

// Round 7
// 347.892 us; speedup vs baseline: 1.2771x; 1.2771x over previous
//
#include <hip/hip_runtime.h>
#include <cstdint>
#include <cstddef>

typedef __bf16 bf16x8 __attribute__((ext_vector_type(8)));
typedef float f32x4 __attribute__((ext_vector_type(4)));
typedef unsigned short u16;
typedef unsigned short u16x8 __attribute__((ext_vector_type(8)));

#define BATCH 4096
#define NE 8

__device__ __forceinline__ u16 f2bf(float f) {
  union { float f; uint32_t u; } v; v.f = f;
  uint32_t u = v.u;
  u += 0x7fffu + ((u >> 16) & 1u);   // RTNE
  return (u16)(u >> 16);
}

__device__ __forceinline__ float bf2f(u16 u) {
  union { uint32_t u; float f; } v; v.u = ((uint32_t)u) << 16;
  return v.f;
}

__device__ __forceinline__ void cast8(const float* src, u16* dst) {
  const float4* p = (const float4*)src;
  float4 a = p[0], b = p[1];
  u16x8 o;
  o[0] = f2bf(a.x); o[1] = f2bf(a.y); o[2] = f2bf(a.z); o[3] = f2bf(a.w);
  o[4] = f2bf(b.x); o[5] = f2bf(b.y); o[6] = f2bf(b.z); o[7] = f2bf(b.w);
  *(u16x8*)dst = o;
}

// One dispatch: h0 = bf16(x); W0/W1/W2 (E,N,K0) fp32 -> Bt (N, E*K0) bf16.
__device__ __forceinline__ void conv_w_chunk(const float* __restrict__ W,
                                             u16* __restrict__ Bt,
                                             int N, int K0, int chunk) {
  int per_row = K0 >> 3;
  int rid = chunk / per_row;             // rid = e*N + o
  int i0 = (chunk - rid * per_row) << 3;
  int e = rid / N;
  int o = rid - e * N;
  cast8(W + (size_t)rid * K0 + i0,
        Bt + (size_t)o * ((size_t)NE * K0) + (size_t)e * K0 + i0);
}

__global__ void prep_kernel(const float* __restrict__ x,
                            const float* __restrict__ W0,
                            const float* __restrict__ W1,
                            const float* __restrict__ W2,
                            u16* __restrict__ h0, u16* __restrict__ Bt0,
                            u16* __restrict__ Bt1, u16* __restrict__ Bt2) {
  int t = blockIdx.x * blockDim.x + threadIdx.x;
  const int C0 = BATCH * 512 / 8;            // x cast:   262144
  const int C1 = C0 + NE * 1024 * 512 / 8;   // W0:      +524288
  const int C2 = C1 + NE * 1024 * 1024 / 8;  // W1:      +1048576
  if (t < C0) {
    cast8(x + (size_t)t * 8, h0 + (size_t)t * 8);
  } else if (t < C1) {
    conv_w_chunk(W0, Bt0, 1024, 512, t - C0);
  } else if (t < C2) {
    conv_w_chunk(W1, Bt1, 1024, 1024, t - C1);
  } else {
    conv_w_chunk(W2, Bt2, 512, 1024, t - C2);
  }
}

// out[b,o] = sum_e blend[b,e]*(P_e[b,o] + Bias[e,o]); optional ELU; bf16 or fp32 out.
template<bool ELU_ACT, bool OUT_BF16>
__global__ void combine8_kernel(const u16* __restrict__ P,
                                const float* __restrict__ blend,
                                const float* __restrict__ Bias,
                                void* __restrict__ outp, int N) {
  int t = blockIdx.x * blockDim.x + threadIdx.x;
  int per_row = N >> 3;
  int b = t / per_row;
  int i0 = (t - b * per_row) << 3;
  const size_t slice = (size_t)BATCH * N;
  const float4* blp = (const float4*)(blend + b * NE);
  float4 u0 = blp[0], u1 = blp[1];
  float bl[8] = {u0.x, u0.y, u0.z, u0.w, u1.x, u1.y, u1.z, u1.w};
  float v[8] = {0, 0, 0, 0, 0, 0, 0, 0};
  #pragma unroll
  for (int e = 0; e < NE; ++e) {
    u16x8 pv = *(const u16x8*)(P + (size_t)e * slice + (size_t)b * N + i0);
    #pragma unroll
    for (int j = 0; j < 8; ++j) v[j] += bl[e] * bf2f(pv[j]);
  }
  #pragma unroll
  for (int e = 0; e < NE; ++e) {
    const float4* bp = (const float4*)(Bias + (size_t)e * N + i0);
    float4 ba = bp[0], bb = bp[1];
    float bv[8] = {ba.x, ba.y, ba.z, ba.w, bb.x, bb.y, bb.z, bb.w};
    #pragma unroll
    for (int j = 0; j < 8; ++j) v[j] += bl[e] * bv[j];
  }
  if (ELU_ACT) {
    #pragma unroll
    for (int j = 0; j < 8; ++j) v[j] = v[j] > 0.f ? v[j] : expm1f(v[j]);
  }
  if (OUT_BF16) {
    u16x8 o;
    #pragma unroll
    for (int j = 0; j < 8; ++j) o[j] = f2bf(v[j]);
    *(u16x8*)((u16*)outp + (size_t)b * N + i0) = o;
  } else {
    float4* op = (float4*)((float*)outp + (size_t)b * N + i0);
    op[0] = (float4){v[0], v[1], v[2], v[3]};
    op[1] = (float4){v[4], v[5], v[6], v[7]};
  }
}

#define GL2LDS(g, l) __builtin_amdgcn_global_load_lds( \
    (__attribute__((address_space(1))) void*)(g),      \
    (__attribute__((address_space(3))) void*)(l), 16, 0, 0)

// Batched-expert GEMM: P_e(M x N) = h(M x K0) @ W_e(N x K0)^T, bf16 partials.
// r5 loop (both operands via global_load_lds, XOR-8 swizzle, BK=64, 0 conflicts)
// + r6 coalesced transpose epilogue (WRITE_SIZE at ideal)
// + XCD-locality swizzle: 1-D grid, bid = rowb*combos + combo, combo=(colb,e).
//   combos % 8 == 0 so bid % 8 == combo % 8: with the %8 round-robin block->XCD
//   heuristic, all 32 row-blocks sharing a B-tile land on ONE XCD; per-XCD B
//   working set = 8 combos x 256 KB = 2 MB < 4 MB L2 -> B reads become L2 hits.
template<int K0, int NB>   // NB = number of 128-wide column tiles
__global__ __launch_bounds__(256, 4)
void gemm_be_kernel(const u16* __restrict__ h, const u16* __restrict__ Bt,
                    u16* __restrict__ P, int N) {
  __shared__ __align__(16) u16 Hs[128 * 64];
  __shared__ __align__(16) u16 Bs[128 * 64];

  const int tid  = threadIdx.x;
  const int w    = tid >> 6, lane = tid & 63;
  const int wm   = w >> 1,   wn   = w & 1;
  const int lrow = lane & 15, quad = lane >> 4;

  const int bid    = blockIdx.x;
  const int combos = NB * NE;
  const int combo  = bid % combos;
  const int rowb   = bid / combos;
  const int e      = combo & 7;
  const int colb   = combo >> 3;
  const int row0 = rowb * 128;
  const int col0 = colb * 128;
  const int EK   = K0 * NE;

  // staging: thread t covers chunk q = t + 256*i (i=0..3) per operand.
  // row = (t>>3) + 32*i, lds chunk pos = t&7, global col8 = (t&7)^((t>>3)&7).
  const int trow = tid >> 3;
  const int tcol = (tid & 7) ^ (trow & 7);
  const u16* gH = h + (size_t)(row0 + trow) * K0 + (tcol << 3);
  const u16* gB = Bt + (size_t)(col0 + trow) * EK + (size_t)e * K0 + (tcol << 3);
  u16* lH = &Hs[tid * 8];
  u16* lB = &Bs[tid * 8];

  // fragment read pointers: logical chunk (kc*4+quad) of row r at ((kc*4+quad)^(r&7))
  const int xr = lrow & 7;
  const u16* fH[2][4];
  const u16* fB[2][4];
  #pragma unroll
  for (int kc = 0; kc < 2; ++kc)
    #pragma unroll
    for (int i = 0; i < 4; ++i) {
      fH[kc][i] = &Hs[(wm * 64 + i * 16 + lrow) * 64 + (((kc * 4 + quad) ^ xr) << 3)];
      fB[kc][i] = &Bs[(wn * 64 + i * 16 + lrow) * 64 + (((kc * 4 + quad) ^ xr) << 3)];
    }

  f32x4 acc[4][4];
  #pragma unroll
  for (int i = 0; i < 4; ++i)
    #pragma unroll
    for (int j = 0; j < 4; ++j) acc[i][j] = (f32x4){0.f, 0.f, 0.f, 0.f};

  for (int it = 0; it < K0 / 64; ++it) {
    #pragma unroll
    for (int i = 0; i < 4; ++i) {
      GL2LDS(gH + (size_t)(32 * i) * K0, lH + 2048 * i);
      GL2LDS(gB + (size_t)(32 * i) * EK, lB + 2048 * i);
    }
    gH += 64; gB += 64;
    __syncthreads();

    #pragma unroll
    for (int kc = 0; kc < 2; ++kc) {
      bf16x8 hf[4], bfr[4];
      #pragma unroll
      for (int i = 0; i < 4; ++i) hf[i] = *(const bf16x8*)fH[kc][i];
      #pragma unroll
      for (int j = 0; j < 4; ++j) bfr[j] = *(const bf16x8*)fB[kc][j];
      #pragma unroll
      for (int i = 0; i < 4; ++i)
        #pragma unroll
        for (int j = 0; j < 4; ++j)
          acc[i][j] = __builtin_amdgcn_mfma_f32_16x16x32_bf16(hf[i], bfr[j], acc[i][j], 0, 0, 0);
    }
    __syncthreads();
  }

  // Coalesced epilogue via per-wave LDS transpose (Hs free after the final
  // barrier above). C/D layout: col = lane&15, row = quad*4 + reg.
  u16* Ps = P + (size_t)e * ((size_t)BATCH * N);
  u16* ls = &Hs[w * 2048];   // 4 KB per wave: 32 rows x 64 cols u16
  #pragma unroll
  for (int half = 0; half < 2; ++half) {
    #pragma unroll
    for (int mh = 0; mh < 2; ++mh) {
      int mt = half * 2 + mh;
      #pragma unroll
      for (int r = 0; r < 4; ++r) {
        int rloc = mh * 16 + quad * 4 + r;          // 0..31
        #pragma unroll
        for (int nt = 0; nt < 4; ++nt) {
          int col = nt * 16 + lrow;                 // 0..63
          int c8 = (col >> 3) ^ (rloc & 7);         // XOR-8 chunk swizzle
          ls[rloc * 64 + (c8 << 3) + (col & 7)] = f2bf(acc[mt][nt][r]);
        }
      }
    }
    // read back transposed: 4 passes of 64 lanes x 8 contiguous u16
    #pragma unroll
    for (int p = 0; p < 4; ++p) {
      int rloc = p * 8 + (lane >> 3);               // 0..31
      int c8 = (lane & 7) ^ (rloc & 7);
      u16x8 v = *(const u16x8*)&ls[rloc * 64 + (c8 << 3)];
      int row = row0 + wm * 64 + half * 32 + rloc;
      int colg = col0 + wn * 64 + ((lane & 7) << 3);
      *(u16x8*)&Ps[(size_t)row * N + colg] = v;
    }
  }
}

extern "C" void kernel_launch(void* const* d_in, const int* in_sizes, int n_in,
                              void* d_out, int out_size, void* d_ws, size_t ws_size,
                              hipStream_t stream) {
  const float* blend = (const float*)d_in[0];
  const float* x  = (const float*)d_in[1];
  const float* W0 = (const float*)d_in[2];
  const float* B0 = (const float*)d_in[3];
  const float* W1 = (const float*)d_in[4];
  const float* B1 = (const float*)d_in[5];
  const float* W2 = (const float*)d_in[6];
  const float* B2 = (const float*)d_in[7];
  float* out = (float*)d_out;

  char* ws = (char*)d_ws;
  u16* hA  = (u16*)ws;                           // h0 (4096x512) then h2 (4096x1024); 8.4 MB
  u16* h1  = (u16*)(ws + 8388608);               // 4096x1024 bf16, 8.4 MB
  u16* Bt0 = (u16*)(ws + 16777216);              // 1024 x 4096 bf16, 8.4 MB
  u16* Bt1 = (u16*)(ws + 25165824);              // 1024 x 8192 bf16, 16.8 MB
  u16* Bt2 = (u16*)(ws + 41943040);              // 512 x 8192 bf16, 8.4 MB
  u16* P   = (u16*)(ws + 50331648);              // bf16 partials, 8 x 4096 x 1024 = 67.1 MB

  // prep: cast x -> h0 and convert all three W to bf16 Bt layout (one dispatch)
  prep_kernel<<<9216, 256, 0, stream>>>(x, W0, W1, W2, hA, Bt0, Bt1, Bt2);

  // Layer 0: K0=512, N=1024; blend+bias+ELU in combine
  gemm_be_kernel<512, 8><<<2048, 256, 0, stream>>>(hA, Bt0, P, 1024);
  combine8_kernel<true, true><<<2048, 256, 0, stream>>>(P, blend, B0, h1, 1024);

  // Layer 1: K0=1024, N=1024
  gemm_be_kernel<1024, 8><<<2048, 256, 0, stream>>>(h1, Bt1, P, 1024);
  combine8_kernel<true, true><<<2048, 256, 0, stream>>>(P, blend, B1, hA, 1024);

  // Layer 2: K0=1024, N=512, linear, fp32 out
  gemm_be_kernel<1024, 4><<<1024, 256, 0, stream>>>(hA, Bt2, P, 512);
  combine8_kernel<false, false><<<1024, 256, 0, stream>>>(P, blend, B2, out, 512);
}

// Round 8
// 287.516 us; speedup vs baseline: 1.5453x; 1.2100x over previous
//
#include <hip/hip_runtime.h>
#include <cstdint>
#include <cstddef>

typedef __bf16 bf16x8 __attribute__((ext_vector_type(8)));
typedef float f32x4 __attribute__((ext_vector_type(4)));
typedef unsigned short u16;
typedef unsigned short u16x8 __attribute__((ext_vector_type(8)));

#define BATCH 4096
#define NE 8

__device__ __forceinline__ u16 f2bf(float f) {
  union { float f; uint32_t u; } v; v.f = f;
  uint32_t u = v.u;
  u += 0x7fffu + ((u >> 16) & 1u);   // RTNE
  return (u16)(u >> 16);
}

__device__ __forceinline__ float bf2f(u16 u) {
  union { uint32_t u; float f; } v; v.u = ((uint32_t)u) << 16;
  return v.f;
}

__device__ __forceinline__ void cast8(const float* src, u16* dst) {
  const float4* p = (const float4*)src;
  float4 a = p[0], b = p[1];
  u16x8 o;
  o[0] = f2bf(a.x); o[1] = f2bf(a.y); o[2] = f2bf(a.z); o[3] = f2bf(a.w);
  o[4] = f2bf(b.x); o[5] = f2bf(b.y); o[6] = f2bf(b.z); o[7] = f2bf(b.w);
  *(u16x8*)dst = o;
}

// One dispatch: h0 = bf16(x); W0/W1/W2 (E,N,K0) fp32 -> Bt (N, E*K0) bf16.
__device__ __forceinline__ void conv_w_chunk(const float* __restrict__ W,
                                             u16* __restrict__ Bt,
                                             int N, int K0, int chunk) {
  int per_row = K0 >> 3;
  int rid = chunk / per_row;             // rid = e*N + o
  int i0 = (chunk - rid * per_row) << 3;
  int e = rid / N;
  int o = rid - e * N;
  cast8(W + (size_t)rid * K0 + i0,
        Bt + (size_t)o * ((size_t)NE * K0) + (size_t)e * K0 + i0);
}

__global__ void prep_kernel(const float* __restrict__ x,
                            const float* __restrict__ W0,
                            const float* __restrict__ W1,
                            const float* __restrict__ W2,
                            u16* __restrict__ h0, u16* __restrict__ Bt0,
                            u16* __restrict__ Bt1, u16* __restrict__ Bt2) {
  int t = blockIdx.x * blockDim.x + threadIdx.x;
  const int C0 = BATCH * 512 / 8;            // x cast:   262144
  const int C1 = C0 + NE * 1024 * 512 / 8;   // W0:      +524288
  const int C2 = C1 + NE * 1024 * 1024 / 8;  // W1:      +1048576
  if (t < C0) {
    cast8(x + (size_t)t * 8, h0 + (size_t)t * 8);
  } else if (t < C1) {
    conv_w_chunk(W0, Bt0, 1024, 512, t - C0);
  } else if (t < C2) {
    conv_w_chunk(W1, Bt1, 1024, 1024, t - C1);
  } else {
    conv_w_chunk(W2, Bt2, 512, 1024, t - C2);
  }
}

// out = [act](sum_s P_s + blend @ Bias), P_s bf16; bf16 or fp32 out.
template<int SLICES, bool ELU_ACT, bool OUT_BF16>
__global__ void combineS_kernel(const u16* __restrict__ P,
                                const float* __restrict__ blend,
                                const float* __restrict__ Bias,
                                void* __restrict__ outp, int N) {
  int t = blockIdx.x * blockDim.x + threadIdx.x;
  int per_row = N >> 3;
  int b = t / per_row;
  int i0 = (t - b * per_row) << 3;
  const size_t slice = (size_t)BATCH * N;
  float v[8] = {0, 0, 0, 0, 0, 0, 0, 0};
  #pragma unroll
  for (int s = 0; s < SLICES; ++s) {
    u16x8 pv = *(const u16x8*)(P + (size_t)s * slice + (size_t)b * N + i0);
    #pragma unroll
    for (int j = 0; j < 8; ++j) v[j] += bf2f(pv[j]);
  }
  const float4* blp = (const float4*)(blend + b * NE);
  float4 u0 = blp[0], u1 = blp[1];
  float bl[8] = {u0.x, u0.y, u0.z, u0.w, u1.x, u1.y, u1.z, u1.w};
  #pragma unroll
  for (int e = 0; e < NE; ++e) {
    const float4* bp = (const float4*)(Bias + (size_t)e * N + i0);
    float4 ba = bp[0], bb = bp[1];
    float bv[8] = {ba.x, ba.y, ba.z, ba.w, bb.x, bb.y, bb.z, bb.w};
    #pragma unroll
    for (int j = 0; j < 8; ++j) v[j] += bl[e] * bv[j];
  }
  if (ELU_ACT) {
    #pragma unroll
    for (int j = 0; j < 8; ++j) v[j] = v[j] > 0.f ? v[j] : expm1f(v[j]);
  }
  if (OUT_BF16) {
    u16x8 o;
    #pragma unroll
    for (int j = 0; j < 8; ++j) o[j] = f2bf(v[j]);
    *(u16x8*)((u16*)outp + (size_t)b * N + i0) = o;
  } else {
    float4* op = (float4*)((float*)outp + (size_t)b * N + i0);
    op[0] = (float4){v[0], v[1], v[2], v[3]};
    op[1] = (float4){v[4], v[5], v[6], v[7]};
  }
}

#define GL2LDS(g, l) __builtin_amdgcn_global_load_lds( \
    (__attribute__((address_space(1))) void*)(g),      \
    (__attribute__((address_space(3))) void*)(l), 16, 0, 0)

// Expert-folding GEMM: P_z(M x N) = sum_{e in slice z} blend[:,e]*(h @ W_e^T).
// BM=BN=128, BK=64, 4 waves (2x2), XOR-8 LDS swizzle (0 conflicts, r5),
// transposed coalesced bf16 epilogue (r6). Per expert: fresh acc2 over K0,
// then fold acc += blend[row,e]*acc2 (64 fmac + 16 LDS-broadcast reads).
// acc+acc2 = 128 acc-regs -> 2 waves/SIMD, grid 512 = 2 blocks/CU resident.
// This removes the 8-slice P round-trip (134 MB/layer -> 34 MB/layer).
template<int K0, int EPB>   // EPB = experts folded per block
__global__ __launch_bounds__(256, 2)
void gemm_fold_kernel(const u16* __restrict__ h, const u16* __restrict__ Bt,
                      const float* __restrict__ blend,
                      u16* __restrict__ P, int N) {
  __shared__ __align__(16) u16 Hs[128 * 64];
  __shared__ __align__(16) u16 Bs[128 * 64];
  __shared__ float bls[128 * 9];   // blend block, stride 9 (bank-conflict-free)

  const int tid  = threadIdx.x;
  const int w    = tid >> 6, lane = tid & 63;
  const int wm   = w >> 1,   wn   = w & 1;
  const int lrow = lane & 15, quad = lane >> 4;

  const int row0 = blockIdx.x * 128;
  const int col0 = blockIdx.y * 128;
  const int e0   = blockIdx.z * EPB;
  const int EK   = K0 * NE;

  // stage blend[row0..row0+127, 0..7] into bls (vector read, scalar writes)
  {
    const float4 bv = ((const float4*)(blend + (size_t)row0 * NE))[tid];
    int row = tid >> 1, c0 = (tid & 1) * 4;
    bls[row * 9 + c0 + 0] = bv.x;
    bls[row * 9 + c0 + 1] = bv.y;
    bls[row * 9 + c0 + 2] = bv.z;
    bls[row * 9 + c0 + 3] = bv.w;
  }

  // staging addresses (XOR-8 swizzle on the global side)
  const int trow = tid >> 3;
  const int tcol = (tid & 7) ^ (trow & 7);
  const u16* gH = h + (size_t)(row0 + trow) * K0 + (tcol << 3);
  const u16* gB = Bt + (size_t)(col0 + trow) * EK + (size_t)e0 * K0 + (tcol << 3);
  u16* lH = &Hs[tid * 8];
  u16* lB = &Bs[tid * 8];

  // fragment read pointers
  const int xr = lrow & 7;
  const u16* fH[2][4];
  const u16* fB[2][4];
  #pragma unroll
  for (int kc = 0; kc < 2; ++kc)
    #pragma unroll
    for (int i = 0; i < 4; ++i) {
      fH[kc][i] = &Hs[(wm * 64 + i * 16 + lrow) * 64 + (((kc * 4 + quad) ^ xr) << 3)];
      fB[kc][i] = &Bs[(wn * 64 + i * 16 + lrow) * 64 + (((kc * 4 + quad) ^ xr) << 3)];
    }

  f32x4 acc[4][4];
  #pragma unroll
  for (int i = 0; i < 4; ++i)
    #pragma unroll
    for (int j = 0; j < 4; ++j) acc[i][j] = (f32x4){0.f, 0.f, 0.f, 0.f};

  #pragma unroll 1
  for (int ee = 0; ee < EPB; ++ee) {
    f32x4 acc2[4][4];
    #pragma unroll
    for (int i = 0; i < 4; ++i)
      #pragma unroll
      for (int j = 0; j < 4; ++j) acc2[i][j] = (f32x4){0.f, 0.f, 0.f, 0.f};

    const u16* pH = gH;
    const u16* pB = gB + (size_t)ee * K0;

    for (int it = 0; it < K0 / 64; ++it) {
      #pragma unroll
      for (int i = 0; i < 4; ++i) {
        GL2LDS(pH + (size_t)(32 * i) * K0, lH + 2048 * i);
        GL2LDS(pB + (size_t)(32 * i) * EK, lB + 2048 * i);
      }
      pH += 64; pB += 64;
      __syncthreads();

      #pragma unroll
      for (int kc = 0; kc < 2; ++kc) {
        bf16x8 hf[4], bfr[4];
        #pragma unroll
        for (int i = 0; i < 4; ++i) hf[i] = *(const bf16x8*)fH[kc][i];
        #pragma unroll
        for (int j = 0; j < 4; ++j) bfr[j] = *(const bf16x8*)fB[kc][j];
        #pragma unroll
        for (int i = 0; i < 4; ++i)
          #pragma unroll
          for (int j = 0; j < 4; ++j)
            acc2[i][j] = __builtin_amdgcn_mfma_f32_16x16x32_bf16(hf[i], bfr[j], acc2[i][j], 0, 0, 0);
      }
      __syncthreads();
    }

    // fold: acc += blend[row, e0+ee] * acc2 (row = wm*64 + mt*16 + quad*4 + r)
    #pragma unroll
    for (int mt = 0; mt < 4; ++mt) {
      float bl[4];
      #pragma unroll
      for (int r = 0; r < 4; ++r)
        bl[r] = bls[(wm * 64 + mt * 16 + quad * 4 + r) * 9 + (e0 + ee)];
      #pragma unroll
      for (int nt = 0; nt < 4; ++nt)
        #pragma unroll
        for (int r = 0; r < 4; ++r)
          acc[mt][nt][r] += bl[r] * acc2[mt][nt][r];
    }
  }

  // Coalesced epilogue via per-wave LDS transpose (Hs free after final barrier;
  // each wave uses its private 4 KB segment). C/D: col=lane&15, row=quad*4+reg.
  u16* Ps = P + (size_t)blockIdx.z * ((size_t)BATCH * N);
  u16* ls = &Hs[w * 2048];   // 32 rows x 64 cols u16 per wave
  #pragma unroll
  for (int half = 0; half < 2; ++half) {
    #pragma unroll
    for (int mh = 0; mh < 2; ++mh) {
      int mt = half * 2 + mh;
      #pragma unroll
      for (int r = 0; r < 4; ++r) {
        int rloc = mh * 16 + quad * 4 + r;          // 0..31
        #pragma unroll
        for (int nt = 0; nt < 4; ++nt) {
          int col = nt * 16 + lrow;                 // 0..63
          int c8 = (col >> 3) ^ (rloc & 7);         // XOR-8 chunk swizzle
          ls[rloc * 64 + (c8 << 3) + (col & 7)] = f2bf(acc[mt][nt][r]);
        }
      }
    }
    #pragma unroll
    for (int p = 0; p < 4; ++p) {
      int rloc = p * 8 + (lane >> 3);               // 0..31
      int c8 = (lane & 7) ^ (rloc & 7);
      u16x8 v = *(const u16x8*)&ls[rloc * 64 + (c8 << 3)];
      int row = row0 + wm * 64 + half * 32 + rloc;
      int colg = col0 + wn * 64 + ((lane & 7) << 3);
      *(u16x8*)&Ps[(size_t)row * N + colg] = v;
    }
  }
}

extern "C" void kernel_launch(void* const* d_in, const int* in_sizes, int n_in,
                              void* d_out, int out_size, void* d_ws, size_t ws_size,
                              hipStream_t stream) {
  const float* blend = (const float*)d_in[0];
  const float* x  = (const float*)d_in[1];
  const float* W0 = (const float*)d_in[2];
  const float* B0 = (const float*)d_in[3];
  const float* W1 = (const float*)d_in[4];
  const float* B1 = (const float*)d_in[5];
  const float* W2 = (const float*)d_in[6];
  const float* B2 = (const float*)d_in[7];
  float* out = (float*)d_out;

  char* ws = (char*)d_ws;
  u16* hA  = (u16*)ws;                           // h0 (4096x512) then h2 (4096x1024); 8.4 MB
  u16* h1  = (u16*)(ws + 8388608);               // 4096x1024 bf16, 8.4 MB
  u16* Bt0 = (u16*)(ws + 16777216);              // 1024 x 4096 bf16, 8.4 MB
  u16* Bt1 = (u16*)(ws + 25165824);              // 1024 x 8192 bf16, 16.8 MB
  u16* Bt2 = (u16*)(ws + 41943040);              // 512 x 8192 bf16, 8.4 MB
  u16* P   = (u16*)(ws + 50331648);              // bf16 partials, <= 4 x 4096 x 512 (L2) / 2 x 4096 x 1024

  // prep: cast x -> h0 and convert all three W to bf16 Bt layout (one dispatch)
  prep_kernel<<<9216, 256, 0, stream>>>(x, W0, W1, W2, hA, Bt0, Bt1, Bt2);

  // Layer 0: K0=512, N=1024; 2 slices x 4 experts folded; bias+ELU in combine
  gemm_fold_kernel<512, 4><<<dim3(32, 8, 2), 256, 0, stream>>>(hA, Bt0, blend, P, 1024);
  combineS_kernel<2, true, true><<<2048, 256, 0, stream>>>(P, blend, B0, h1, 1024);

  // Layer 1: K0=1024, N=1024; 2 slices x 4 experts
  gemm_fold_kernel<1024, 4><<<dim3(32, 8, 2), 256, 0, stream>>>(h1, Bt1, blend, P, 1024);
  combineS_kernel<2, true, true><<<2048, 256, 0, stream>>>(P, blend, B1, hA, 1024);

  // Layer 2: K0=1024, N=512; 4 slices x 2 experts; linear, fp32 out
  gemm_fold_kernel<1024, 2><<<dim3(32, 4, 4), 256, 0, stream>>>(hA, Bt2, blend, P, 512);
  combineS_kernel<4, false, false><<<1024, 256, 0, stream>>>(P, blend, B2, out, 512);
}